// Round 2
// baseline (936.776 us; speedup 1.0000x reference)
//
#include <hip/hip_runtime.h>

#define B_ 2
#define S_ 4096
#define D_ 2048
#define M_ (B_ * S_)            // 8192 rows
#define EPSV 1e-6f
#define CT 64                   // scan chunk length
#define NCHUNK (S_ / CT)        // 64
#define LOG_NCHUNK 6

static_assert(NCHUNK == (1 << LOG_NCHUNK), "chunk math");

#define BM 128
#define BN 128
#define BK 32

typedef __bf16 bf16x8 __attribute__((ext_vector_type(8)));
typedef __bf16 bf16x4 __attribute__((ext_vector_type(4)));
typedef float  f32x4  __attribute__((ext_vector_type(4)));

// Static device scratch. Every buffer below is FULLY REWRITTEN from d_in inside
// each kernel_launch call, before any kernel reads it (stream-ordered):
//   k_pre  -> g_gate        k_wt -> g_WtA/g_WtB
//   k_gemm -> g_alpha/g_x   k_scan1 -> g_pa/g_ph   (k_scan2 rewrites g_ph)
// so the pipeline is a pure function of d_in; no cross-call state is read.
// d_out is WRITE-ONLY everywhere (no kernel reads d_out).
__device__ __bf16 g_gate[(size_t)M_ * D_];     // 32 MiB  rms(c)+rms(pf) in bf16
__device__ __bf16 g_WtA[(size_t)D_ * D_];      // 8 MiB   W_alpha^T bf16  [n][k]
__device__ __bf16 g_WtB[(size_t)D_ * D_];      // 8 MiB   W_beta^T bf16   [n][k]
__device__ float  g_alpha[(size_t)M_ * D_];    // 64 MiB  sigmoid gate
__device__ float  g_x[(size_t)M_ * D_];        // 64 MiB  v*beta*write_scale
__device__ float  g_pa[B_ * NCHUNK * D_];      // chunk alpha-products
__device__ float  g_ph[B_ * NCHUNK * D_];      // chunk local h_end -> carry-in

// ---------------- K1: rms_norm(c) + rms_norm(pf) -> gate (bf16); also c_out = c ----
__global__ __launch_bounds__(256) void k_pre(const float* __restrict__ c,
                                             const float* __restrict__ pf,
                                             float* __restrict__ c_out) {
  const int row = blockIdx.x;
  const int t = threadIdx.x;
  const size_t rb = (size_t)row * D_;
  const float4* c4 = (const float4*)(c + rb);
  const float4* p4 = (const float4*)(pf + rb);
  float4 cv0 = c4[t], cv1 = c4[t + 256];
  float4 pv0 = p4[t], pv1 = p4[t + 256];
  float ssc = cv0.x*cv0.x + cv0.y*cv0.y + cv0.z*cv0.z + cv0.w*cv0.w
            + cv1.x*cv1.x + cv1.y*cv1.y + cv1.z*cv1.z + cv1.w*cv1.w;
  float ssp = pv0.x*pv0.x + pv0.y*pv0.y + pv0.z*pv0.z + pv0.w*pv0.w
            + pv1.x*pv1.x + pv1.y*pv1.y + pv1.z*pv1.z + pv1.w*pv1.w;
  #pragma unroll
  for (int off = 32; off; off >>= 1) {
    ssc += __shfl_down(ssc, off);
    ssp += __shfl_down(ssp, off);
  }
  __shared__ float red[8];
  const int wave = t >> 6, lane = t & 63;
  if (lane == 0) { red[wave] = ssc; red[wave + 4] = ssp; }
  __syncthreads();
  const float sc = red[0] + red[1] + red[2] + red[3];
  const float sp = red[4] + red[5] + red[6] + red[7];
  const float rc = rsqrtf(sc * (1.0f / D_) + EPSV);
  const float rp = rsqrtf(sp * (1.0f / D_) + EPSV);
  bf16x4 o0 = { (__bf16)(cv0.x*rc + pv0.x*rp), (__bf16)(cv0.y*rc + pv0.y*rp),
                (__bf16)(cv0.z*rc + pv0.z*rp), (__bf16)(cv0.w*rc + pv0.w*rp) };
  bf16x4 o1 = { (__bf16)(cv1.x*rc + pv1.x*rp), (__bf16)(cv1.y*rc + pv1.y*rp),
                (__bf16)(cv1.z*rc + pv1.z*rp), (__bf16)(cv1.w*rc + pv1.w*rp) };
  *(bf16x4*)(g_gate + rb + 4 * t) = o0;
  *(bf16x4*)(g_gate + rb + 1024 + 4 * t) = o1;
  // c_out is never re-read on device -> non-temporal (cast to clang ext_vector)
  f32x4* co = (f32x4*)(c_out + rb);
  __builtin_nontemporal_store(*(const f32x4*)&cv0, co + t);
  __builtin_nontemporal_store(*(const f32x4*)&cv1, co + t + 256);
}

// ---------------- K2: transpose + fp32->bf16 both weight matrices -------------------
__global__ __launch_bounds__(256) void k_wt(const float* __restrict__ Wa,
                                            const float* __restrict__ Wb) {
  __shared__ float tile[32][33];
  const float* W = blockIdx.z ? Wb : Wa;
  __bf16* outp = blockIdx.z ? g_WtB : g_WtA;
  const int n0 = blockIdx.x * 32, k0 = blockIdx.y * 32;
  for (int i = threadIdx.y; i < 32; i += 8)
    tile[i][threadIdx.x] = W[(size_t)(k0 + i) * D_ + n0 + threadIdx.x];
  __syncthreads();
  for (int i = threadIdx.y; i < 32; i += 8)
    outp[(size_t)(n0 + i) * D_ + k0 + threadIdx.x] = (__bf16)tile[threadIdx.x][i];
}

// ---------------- K3: dual bf16 MFMA GEMM + activation epilogue ---------------------
__device__ __forceinline__ void gld16(const void* g, void* l) {
  __builtin_amdgcn_global_load_lds((const __attribute__((address_space(1))) void*)g,
                                   (__attribute__((address_space(3))) void*)l, 16, 0, 0);
}
__device__ __forceinline__ f32x4 mfma16(bf16x8 a, bf16x8 b, f32x4 c) {
  return __builtin_amdgcn_mfma_f32_16x16x32_bf16(a, b, c, 0, 0, 0);
}

__global__ __launch_bounds__(256) void k_gemm(const float* __restrict__ v,
                                              const float* __restrict__ bia,
                                              const float* __restrict__ bib) {
  __shared__ __bf16 sA[BM * BK];
  __shared__ __bf16 sBa[BN * BK];
  __shared__ __bf16 sBb[BN * BK];
  const int tid = threadIdx.x;
  const int wave = tid >> 6, lane = tid & 63;
  const int bm = blockIdx.x, bn = blockIdx.y;
  const int wm = (wave >> 1) * 64, wn = (wave & 1) * 64;
  const int qd = lane >> 4, ln = lane & 15;

  const __bf16* gA  = g_gate + (size_t)(bm * BM) * D_;
  const __bf16* gBa = g_WtA + (size_t)(bn * BN) * D_;
  const __bf16* gBb = g_WtB + (size_t)(bn * BN) * D_;
  const int sr = tid >> 2;            // staging row 0..63 (and +64)
  const int scc = (tid & 3) * 8;      // staging col (elements)
  char* sAc = (char*)sA; char* sBac = (char*)sBa; char* sBbc = (char*)sBb;
  const int wb = wave * 1024;

  f32x4 acc_a[4][4], acc_b[4][4];
  #pragma unroll
  for (int i = 0; i < 4; i++)
    #pragma unroll
    for (int j = 0; j < 4; j++) {
      acc_a[i][j] = (f32x4){0.f, 0.f, 0.f, 0.f};
      acc_b[i][j] = (f32x4){0.f, 0.f, 0.f, 0.f};
    }

  for (int k0 = 0; k0 < D_; k0 += BK) {
    __syncthreads();
    gld16(gA  + (size_t)sr * D_ + k0 + scc,        sAc + wb);
    gld16(gA  + (size_t)(sr + 64) * D_ + k0 + scc, sAc + 4096 + wb);
    gld16(gBa + (size_t)sr * D_ + k0 + scc,        sBac + wb);
    gld16(gBa + (size_t)(sr + 64) * D_ + k0 + scc, sBac + 4096 + wb);
    gld16(gBb + (size_t)sr * D_ + k0 + scc,        sBbc + wb);
    gld16(gBb + (size_t)(sr + 64) * D_ + k0 + scc, sBbc + 4096 + wb);
    __syncthreads();
    bf16x8 af[4], bA[4], bB[4];
    #pragma unroll
    for (int i = 0; i < 4; i++)
      af[i] = *(const bf16x8*)(sA + (wm + i * 16 + ln) * BK + qd * 8);
    #pragma unroll
    for (int j = 0; j < 4; j++) {
      bA[j] = *(const bf16x8*)(sBa + (wn + j * 16 + ln) * BK + qd * 8);
      bB[j] = *(const bf16x8*)(sBb + (wn + j * 16 + ln) * BK + qd * 8);
    }
    #pragma unroll
    for (int i = 0; i < 4; i++)
      #pragma unroll
      for (int j = 0; j < 4; j++) {
        acc_a[i][j] = mfma16(af[i], bA[j], acc_a[i][j]);
        acc_b[i][j] = mfma16(af[i], bB[j], acc_b[i][j]);
      }
  }

  // epilogue: alpha = sigmoid(za), beta = silu(zb), x = v*beta*sqrt(max(1-a^2,1e-6))
  #pragma unroll
  for (int j = 0; j < 4; j++) {
    const int gn = bn * BN + wn + j * 16 + ln;
    const float baj = bia[gn], bbj = bib[gn];
    #pragma unroll
    for (int i = 0; i < 4; i++) {
      #pragma unroll
      for (int r = 0; r < 4; r++) {
        const int gm = bm * BM + wm + i * 16 + qd * 4 + r;
        const size_t idx = (size_t)gm * D_ + gn;
        const float za = acc_a[i][j][r] + baj;
        const float alpha = 1.0f / (1.0f + __expf(-za));
        const float zb = acc_b[i][j][r] + bbj;
        const float beta = zb / (1.0f + __expf(-zb));
        const float wsq = sqrtf(fmaxf(1.0f - alpha * alpha, 1e-6f));
        g_alpha[idx] = alpha;
        g_x[idx] = v[idx] * beta * wsq;
      }
    }
  }
}

// ---------------- K4a: chunk-local (alpha product, local scan end) ------------------
__global__ __launch_bounds__(256) void k_scan1() {
  const int bid = blockIdx.x;
  const int dblk = bid & 7;
  const int cg = bid >> 3;
  const int chunk = cg & (NCHUNK - 1);
  const int b = cg >> LOG_NCHUNK;
  const int d = dblk * 256 + threadIdx.x;
  const size_t base = ((size_t)b * S_ + (size_t)chunk * CT) * D_ + d;
  float h = 0.f, p = 1.f;
  #pragma unroll 4
  for (int t = 0; t < CT; ++t) {
    const float a = g_alpha[base + (size_t)t * D_];
    const float x = g_x[base + (size_t)t * D_];
    h = a * h + x;
    p *= a;
  }
  const int pi = (b * NCHUNK + chunk) * D_ + d;
  g_pa[pi] = p;
  g_ph[pi] = h;
}

// ---------------- K4b: inter-chunk sequential scan; g_ph becomes carry-in -----------
__global__ __launch_bounds__(256) void k_scan2() {
  const int ch = blockIdx.x * 256 + threadIdx.x;   // 0..B*D-1
  const int b = ch >> 11, dd = ch & (D_ - 1);
  float carry = 0.f;
  #pragma unroll
  for (int chunk = 0; chunk < NCHUNK; ++chunk) {
    const int pi = (b * NCHUNK + chunk) * D_ + dd;
    const float p = g_pa[pi];
    const float h = g_ph[pi];
    g_ph[pi] = carry;            // carry-in for this chunk
    carry = p * carry + h;
  }
}

// ---------------- K4c: rescan with carry-in + all output writes ---------------------
__global__ __launch_bounds__(256) void k_scan3(const float* __restrict__ v,
                                               const float* __restrict__ outp,
                                               const float* __restrict__ go_,
                                               const float* __restrict__ gv_,
                                               float* __restrict__ v_new,
                                               float* __restrict__ out_new,
                                               float* __restrict__ fetched) {
  const int bid = blockIdx.x;
  const int dblk = bid & 7;
  const int cg = bid >> 3;
  const int chunk = cg & (NCHUNK - 1);
  const int b = cg >> LOG_NCHUNK;
  const int d = dblk * 256 + threadIdx.x;
  const int pi = (b * NCHUNK + chunk) * D_ + d;
  float h = g_ph[pi];
  const float go = go_[d], gv = gv_[d];
  const size_t base = ((size_t)b * S_ + (size_t)chunk * CT) * D_ + d;
  #pragma unroll 4
  for (int t = 0; t < CT; ++t) {
    const size_t idx = base + (size_t)t * D_;
    const float a = g_alpha[idx];
    const float x = g_x[idx];
    h = a * h + x;
    // final outputs are never re-read on device -> non-temporal stores
    __builtin_nontemporal_store(h, fetched + idx);
    __builtin_nontemporal_store(outp[idx] + h * go, out_new + idx);
    __builtin_nontemporal_store(v[idx] + h * gv, v_new + idx);
  }
}

extern "C" void kernel_launch(void* const* d_in, const int* in_sizes, int n_in,
                              void* d_out, int out_size, void* d_ws, size_t ws_size,
                              hipStream_t stream) {
  const float* v   = (const float*)d_in[0];
  const float* out = (const float*)d_in[1];
  const float* c   = (const float*)d_in[2];
  const float* pf  = (const float*)d_in[3];
  const float* Wa  = (const float*)d_in[4];
  const float* ba  = (const float*)d_in[5];
  const float* Wb  = (const float*)d_in[6];
  const float* bb  = (const float*)d_in[7];
  const float* go  = (const float*)d_in[8];
  const float* gv  = (const float*)d_in[9];

  float* obase = (float*)d_out;
  const size_t BSD = (size_t)B_ * S_ * D_;
  float* v_new   = obase;
  float* out_new = obase + BSD;
  float* c_out   = obase + 2 * BSD;
  float* fetched = obase + 3 * BSD;

  hipLaunchKernelGGL(k_wt,   dim3(D_ / 32, D_ / 32, 2), dim3(32, 8), 0, stream, Wa, Wb);
  hipLaunchKernelGGL(k_pre,  dim3(M_), dim3(256), 0, stream, c, pf, c_out);
  hipLaunchKernelGGL(k_gemm, dim3(M_ / BM, D_ / BN), dim3(256), 0, stream, v, ba, bb);
  hipLaunchKernelGGL(k_scan1, dim3(B_ * NCHUNK * (D_ / 256)), dim3(256), 0, stream);
  hipLaunchKernelGGL(k_scan2, dim3((B_ * D_) / 256), dim3(256), 0, stream);
  hipLaunchKernelGGL(k_scan3, dim3(B_ * NCHUNK * (D_ / 256)), dim3(256), 0, stream,
                     v, out, go, gv, v_new, out_new, fetched);
}

// Round 3
// 819.223 us; speedup vs baseline: 1.1435x; 1.1435x over previous
//
#include <hip/hip_runtime.h>

#define B_ 2
#define S_ 4096
#define D_ 2048
#define M_ (B_ * S_)            // 8192 rows
#define EPSV 1e-6f
#define CT 64                   // scan chunk length
#define NCHUNK (S_ / CT)        // 64
#define LOG_NCHUNK 6

static_assert(NCHUNK == (1 << LOG_NCHUNK), "chunk math");

#define BM 128
#define BN 128
#define BK 32
#define NB_ (D_ / BN)           // 16 column-blocks per matrix

typedef __bf16 bf16x8 __attribute__((ext_vector_type(8)));
typedef __bf16 bf16x4 __attribute__((ext_vector_type(4)));
typedef float  f32x4  __attribute__((ext_vector_type(4)));

// Static device scratch. Every buffer below is FULLY REWRITTEN from d_in inside
// each kernel_launch call, before any kernel reads it (stream-ordered):
//   k_pre  -> g_gate        k_wt -> g_WtA/g_WtB
//   k_gemm -> g_alpha/g_bv  k_scan1 -> g_pa/g_ph   (k_scan2 rewrites g_ph)
// so the pipeline is a pure function of d_in; no cross-call state is read.
// d_out is WRITE-ONLY everywhere (no kernel reads d_out).
__device__ __bf16 g_gate[(size_t)M_ * D_];     // 32 MiB  rms(c)+rms(pf) in bf16
__device__ __bf16 g_WtA[(size_t)D_ * D_];      // 8 MiB   W_alpha^T bf16  [n][k]
__device__ __bf16 g_WtB[(size_t)D_ * D_];      // 8 MiB   W_beta^T bf16   [n][k]
__device__ float  g_alpha[(size_t)M_ * D_];    // 64 MiB  sigmoid gate
__device__ float  g_bv[(size_t)M_ * D_];       // 64 MiB  v*silu(zb); x computed in scans
__device__ float  g_pa[B_ * NCHUNK * D_];      // chunk alpha-products
__device__ float  g_ph[B_ * NCHUNK * D_];      // chunk local h_end -> carry-in

// ---------------- K1: rms_norm(c) + rms_norm(pf) -> gate (bf16); also c_out = c ----
__global__ __launch_bounds__(256) void k_pre(const float* __restrict__ c,
                                             const float* __restrict__ pf,
                                             float* __restrict__ c_out) {
  const int row = blockIdx.x;
  const int t = threadIdx.x;
  const size_t rb = (size_t)row * D_;
  const float4* c4 = (const float4*)(c + rb);
  const float4* p4 = (const float4*)(pf + rb);
  float4 cv0 = c4[t], cv1 = c4[t + 256];
  float4 pv0 = p4[t], pv1 = p4[t + 256];
  float ssc = cv0.x*cv0.x + cv0.y*cv0.y + cv0.z*cv0.z + cv0.w*cv0.w
            + cv1.x*cv1.x + cv1.y*cv1.y + cv1.z*cv1.z + cv1.w*cv1.w;
  float ssp = pv0.x*pv0.x + pv0.y*pv0.y + pv0.z*pv0.z + pv0.w*pv0.w
            + pv1.x*pv1.x + pv1.y*pv1.y + pv1.z*pv1.z + pv1.w*pv1.w;
  #pragma unroll
  for (int off = 32; off; off >>= 1) {
    ssc += __shfl_down(ssc, off);
    ssp += __shfl_down(ssp, off);
  }
  __shared__ float red[8];
  const int wave = t >> 6, lane = t & 63;
  if (lane == 0) { red[wave] = ssc; red[wave + 4] = ssp; }
  __syncthreads();
  const float sc = red[0] + red[1] + red[2] + red[3];
  const float sp = red[4] + red[5] + red[6] + red[7];
  const float rc = rsqrtf(sc * (1.0f / D_) + EPSV);
  const float rp = rsqrtf(sp * (1.0f / D_) + EPSV);
  bf16x4 o0 = { (__bf16)(cv0.x*rc + pv0.x*rp), (__bf16)(cv0.y*rc + pv0.y*rp),
                (__bf16)(cv0.z*rc + pv0.z*rp), (__bf16)(cv0.w*rc + pv0.w*rp) };
  bf16x4 o1 = { (__bf16)(cv1.x*rc + pv1.x*rp), (__bf16)(cv1.y*rc + pv1.y*rp),
                (__bf16)(cv1.z*rc + pv1.z*rp), (__bf16)(cv1.w*rc + pv1.w*rp) };
  *(bf16x4*)(g_gate + rb + 4 * t) = o0;
  *(bf16x4*)(g_gate + rb + 1024 + 4 * t) = o1;
  // c_out is never re-read on device -> non-temporal (cast to clang ext_vector)
  f32x4* co = (f32x4*)(c_out + rb);
  __builtin_nontemporal_store(*(const f32x4*)&cv0, co + t);
  __builtin_nontemporal_store(*(const f32x4*)&cv1, co + t + 256);
}

// ---------------- K2: transpose + fp32->bf16 both weight matrices -------------------
__global__ __launch_bounds__(256) void k_wt(const float* __restrict__ Wa,
                                            const float* __restrict__ Wb) {
  __shared__ float tile[32][33];
  const float* W = blockIdx.z ? Wb : Wa;
  __bf16* outp = blockIdx.z ? g_WtB : g_WtA;
  const int n0 = blockIdx.x * 32, k0 = blockIdx.y * 32;
  for (int i = threadIdx.y; i < 32; i += 8)
    tile[i][threadIdx.x] = W[(size_t)(k0 + i) * D_ + n0 + threadIdx.x];
  __syncthreads();
  for (int i = threadIdx.y; i < 32; i += 8)
    outp[(size_t)(n0 + i) * D_ + k0 + threadIdx.x] = (__bf16)tile[threadIdx.x][i];
}

// ---------------- K3: single wide bf16 MFMA GEMM (m97 structure) --------------------
// N-space is [0,4096): n<2048 -> alpha columns (W_alpha^T), else beta columns
// (W_beta^T). Alpha blocks store sigmoid; beta blocks store v*silu. The
// x = bv*sqrt(max(1-a^2,eps)) product is recomputed in the (BW-bound) scan kernels.
__device__ __forceinline__ void gld16(const void* g, void* l) {
  __builtin_amdgcn_global_load_lds((const __attribute__((address_space(1))) void*)g,
                                   (__attribute__((address_space(3))) void*)l, 16, 0, 0);
}
__device__ __forceinline__ f32x4 mfma16(bf16x8 a, bf16x8 b, f32x4 c) {
  return __builtin_amdgcn_mfma_f32_16x16x32_bf16(a, b, c, 0, 0, 0);
}

__global__ __launch_bounds__(256) void k_gemm(const float* __restrict__ v,
                                              const float* __restrict__ bia,
                                              const float* __restrict__ bib) {
  __shared__ __bf16 sA[BM * BK];   // 8 KB
  __shared__ __bf16 sB[BN * BK];   // 8 KB
  const int tid = threadIdx.x;
  const int wave = tid >> 6, lane = tid & 63;
  const int bm = blockIdx.x, bn = blockIdx.y;
  const int isBeta = bn >= NB_;
  const int bnl = isBeta ? bn - NB_ : bn;
  const int wm = (wave >> 1) * 64, wn = (wave & 1) * 64;
  const int qd = lane >> 4, ln = lane & 15;

  const __bf16* gA = g_gate + (size_t)(bm * BM) * D_;
  const __bf16* gB = (isBeta ? g_WtB : g_WtA) + (size_t)(bnl * BN) * D_;
  const int sr = tid >> 2;            // staging row 0..63 (and +64)
  const int scc = (tid & 3) * 8;      // staging col (elements)
  char* sAc = (char*)sA; char* sBc = (char*)sB;
  const int wb = wave * 1024;

  f32x4 acc[4][4];
  #pragma unroll
  for (int i = 0; i < 4; i++)
    #pragma unroll
    for (int j = 0; j < 4; j++)
      acc[i][j] = (f32x4){0.f, 0.f, 0.f, 0.f};

  for (int k0 = 0; k0 < D_; k0 += BK) {
    __syncthreads();
    gld16(gA + (size_t)sr * D_ + k0 + scc,        sAc + wb);
    gld16(gA + (size_t)(sr + 64) * D_ + k0 + scc, sAc + 4096 + wb);
    gld16(gB + (size_t)sr * D_ + k0 + scc,        sBc + wb);
    gld16(gB + (size_t)(sr + 64) * D_ + k0 + scc, sBc + 4096 + wb);
    __syncthreads();
    bf16x8 af[4], bf[4];
    #pragma unroll
    for (int i = 0; i < 4; i++)
      af[i] = *(const bf16x8*)(sA + (wm + i * 16 + ln) * BK + qd * 8);
    #pragma unroll
    for (int j = 0; j < 4; j++)
      bf[j] = *(const bf16x8*)(sB + (wn + j * 16 + ln) * BK + qd * 8);
    #pragma unroll
    for (int i = 0; i < 4; i++)
      #pragma unroll
      for (int j = 0; j < 4; j++)
        acc[i][j] = mfma16(af[i], bf[j], acc[i][j]);
  }

  if (!isBeta) {
    // alpha = sigmoid(za)
    #pragma unroll
    for (int j = 0; j < 4; j++) {
      const int gn = bnl * BN + wn + j * 16 + ln;
      const float baj = bia[gn];
      #pragma unroll
      for (int i = 0; i < 4; i++) {
        #pragma unroll
        for (int r = 0; r < 4; r++) {
          const int gm = bm * BM + wm + i * 16 + qd * 4 + r;
          const size_t idx = (size_t)gm * D_ + gn;
          const float za = acc[i][j][r] + baj;
          g_alpha[idx] = 1.0f / (1.0f + __expf(-za));
        }
      }
    }
  } else {
    // bv = v * silu(zb)
    #pragma unroll
    for (int j = 0; j < 4; j++) {
      const int gn = bnl * BN + wn + j * 16 + ln;
      const float bbj = bib[gn];
      #pragma unroll
      for (int i = 0; i < 4; i++) {
        #pragma unroll
        for (int r = 0; r < 4; r++) {
          const int gm = bm * BM + wm + i * 16 + qd * 4 + r;
          const size_t idx = (size_t)gm * D_ + gn;
          const float zb = acc[i][j][r] + bbj;
          const float beta = zb / (1.0f + __expf(-zb));
          g_bv[idx] = v[idx] * beta;
        }
      }
    }
  }
}

// ---------------- K4a: chunk-local (alpha product, local scan end) ------------------
__global__ __launch_bounds__(256) void k_scan1() {
  const int bid = blockIdx.x;
  const int dblk = bid & 7;
  const int cg = bid >> 3;
  const int chunk = cg & (NCHUNK - 1);
  const int b = cg >> LOG_NCHUNK;
  const int d = dblk * 256 + threadIdx.x;
  const size_t base = ((size_t)b * S_ + (size_t)chunk * CT) * D_ + d;
  float h = 0.f, p = 1.f;
  #pragma unroll 4
  for (int t = 0; t < CT; ++t) {
    const float a = g_alpha[base + (size_t)t * D_];
    const float bv = g_bv[base + (size_t)t * D_];
    const float x = bv * sqrtf(fmaxf(1.0f - a * a, 1e-6f));
    h = a * h + x;
    p *= a;
  }
  const int pi = (b * NCHUNK + chunk) * D_ + d;
  g_pa[pi] = p;
  g_ph[pi] = h;
}

// ---------------- K4b: inter-chunk sequential scan; g_ph becomes carry-in -----------
__global__ __launch_bounds__(256) void k_scan2() {
  const int ch = blockIdx.x * 256 + threadIdx.x;   // 0..B*D-1
  const int b = ch >> 11, dd = ch & (D_ - 1);
  float carry = 0.f;
  #pragma unroll
  for (int chunk = 0; chunk < NCHUNK; ++chunk) {
    const int pi = (b * NCHUNK + chunk) * D_ + dd;
    const float p = g_pa[pi];
    const float h = g_ph[pi];
    g_ph[pi] = carry;            // carry-in for this chunk
    carry = p * carry + h;
  }
}

// ---------------- K4c: rescan with carry-in + all output writes ---------------------
__global__ __launch_bounds__(256) void k_scan3(const float* __restrict__ v,
                                               const float* __restrict__ outp,
                                               const float* __restrict__ go_,
                                               const float* __restrict__ gv_,
                                               float* __restrict__ v_new,
                                               float* __restrict__ out_new,
                                               float* __restrict__ fetched) {
  const int bid = blockIdx.x;
  const int dblk = bid & 7;
  const int cg = bid >> 3;
  const int chunk = cg & (NCHUNK - 1);
  const int b = cg >> LOG_NCHUNK;
  const int d = dblk * 256 + threadIdx.x;
  const int pi = (b * NCHUNK + chunk) * D_ + d;
  float h = g_ph[pi];
  const float go = go_[d], gv = gv_[d];
  const size_t base = ((size_t)b * S_ + (size_t)chunk * CT) * D_ + d;
  #pragma unroll 4
  for (int t = 0; t < CT; ++t) {
    const size_t idx = base + (size_t)t * D_;
    const float a = g_alpha[idx];
    const float bv = g_bv[idx];
    const float x = bv * sqrtf(fmaxf(1.0f - a * a, 1e-6f));
    h = a * h + x;
    // final outputs are never re-read on device -> non-temporal stores
    __builtin_nontemporal_store(h, fetched + idx);
    __builtin_nontemporal_store(outp[idx] + h * go, out_new + idx);
    __builtin_nontemporal_store(v[idx] + h * gv, v_new + idx);
  }
}

extern "C" void kernel_launch(void* const* d_in, const int* in_sizes, int n_in,
                              void* d_out, int out_size, void* d_ws, size_t ws_size,
                              hipStream_t stream) {
  const float* v   = (const float*)d_in[0];
  const float* out = (const float*)d_in[1];
  const float* c   = (const float*)d_in[2];
  const float* pf  = (const float*)d_in[3];
  const float* Wa  = (const float*)d_in[4];
  const float* ba  = (const float*)d_in[5];
  const float* Wb  = (const float*)d_in[6];
  const float* bb  = (const float*)d_in[7];
  const float* go  = (const float*)d_in[8];
  const float* gv  = (const float*)d_in[9];

  float* obase = (float*)d_out;
  const size_t BSD = (size_t)B_ * S_ * D_;
  float* v_new   = obase;
  float* out_new = obase + BSD;
  float* c_out   = obase + 2 * BSD;
  float* fetched = obase + 3 * BSD;

  hipLaunchKernelGGL(k_wt,   dim3(D_ / 32, D_ / 32, 2), dim3(32, 8), 0, stream, Wa, Wb);
  hipLaunchKernelGGL(k_pre,  dim3(M_), dim3(256), 0, stream, c, pf, c_out);
  hipLaunchKernelGGL(k_gemm, dim3(M_ / BM, 2 * NB_), dim3(256), 0, stream, v, ba, bb);
  hipLaunchKernelGGL(k_scan1, dim3(B_ * NCHUNK * (D_ / 256)), dim3(256), 0, stream);
  hipLaunchKernelGGL(k_scan2, dim3((B_ * D_) / 256), dim3(256), 0, stream);
  hipLaunchKernelGGL(k_scan3, dim3(B_ * NCHUNK * (D_ / 256)), dim3(256), 0, stream,
                     v, out, go, gv, v_new, out_new, fetched);
}